// Round 1
// 777.914 us; speedup vs baseline: 1.0185x; 1.0185x over previous
//
#include <hip/hip_runtime.h>
#include <hip/hip_bf16.h>
#include <stdint.h>
#include <stddef.h>

typedef __bf16 bf16;
typedef __bf16 bf16x8 __attribute__((ext_vector_type(8)));
typedef float f32x4 __attribute__((ext_vector_type(4)));
typedef __attribute__((address_space(1))) void gvoid;
typedef __attribute__((address_space(3))) void lvoid;

#define FENCE() asm volatile("" ::: "memory")
#define VMCNT(n) asm volatile("s_waitcnt vmcnt(" #n ")" ::: "memory")
#define BARS() do { FENCE(); __builtin_amdgcn_s_barrier(); FENCE(); } while (0)

// ---------------- fp32 -> bf16 elementwise convert, 8 elem/thread ----------------
__global__ __launch_bounds__(256)
void cvt_f32_bf16(const float* __restrict__ in, bf16* __restrict__ out, int n8)
{
    int i = blockIdx.x * 256 + threadIdx.x;
    if (i >= n8) return;
    const f32x4* p = (const f32x4*)in + (size_t)i * 2;
    f32x4 a = p[0], b = p[1];
    bf16x8 o;
    o[0] = (bf16)a[0]; o[1] = (bf16)a[1]; o[2] = (bf16)a[2]; o[3] = (bf16)a[3];
    o[4] = (bf16)b[0]; o[5] = (bf16)b[1]; o[6] = (bf16)b[2]; o[7] = (bf16)b[3];
    *((bf16x8*)out + i) = o;
}

// ---------------- 256x256 / BK=64 / 8-wave / 8-phase GEMM ----------------
// C[M,N] = act(A[M,K] * B[N,K]^T + bias1 (+bias2)). bf16 in, fp32 MFMA accum.
// Requires M%256==0, N%256==0, K%128==0.
//
// LDS (128 KiB dynamic): A = 2 bufs x 2 halves x [128 rows][64 cols] bf16,
// B same. Region (buf,h) base = (buf*2+h)*8192 elems. Swizzle: LDS row r,
// slot s (16B granule) holds global k-granule s ^ (r&7); written by putting
// the XOR on the global_load_lds SOURCE address (dest must stay linear,
// m104/m108), read back with the same XOR. Measured 0 bank conflicts.
//
// Schedule (per iteration = 2 K-tiles; P=buf0 even tiles, Q=buf1 odd):
//   ph1: rd A(m0-3)+B(n0-1) of P | stage Q.A0(t1) | bar | 16 MFMA | bar
//   ph2: rd B(n2-3) of P         | stage Q.A1(t1) | ...
//   ph3: rd A(m4-7) of P         | stage P.B0(t2)
//   ph4:                           stage P.B1(t2) | vmcnt(4)
//   ph5-8: same on Q, staging P.A0(t2), P.A1(t2), Q.B0(t3), Q.B1(t3),
//          vmcnt(4) at ph8.
// Each stage targets a region whose last ds_read completed >=1 closing
// barrier earlier. vmcnt(4) = allow exactly the 2 half-tiles (4 loads)
// issued since the data being waited on. Tail: t2/t3 clamp to tile 0
// (in-bounds garbage into dead regions) so counts stay uniform; vmcnt(0)
// after the loop so no LDS write lands after dealloc.
#define RDA(buf, mh) \
    _Pragma("unroll") \
    for (int m_ = 0; m_ < 4; ++m_) { \
        const int r_ = ((mh) + m_) * 16 + frow; \
        af[m_][0] = *(const bf16x8*)&As[(buf)*16384 + wr*8192 + r_*64 + ((fg     ^ (r_ & 7)) * 8)]; \
        af[m_][1] = *(const bf16x8*)&As[(buf)*16384 + wr*8192 + r_*64 + (((fg+4) ^ (r_ & 7)) * 8)]; \
    }

#define RDB(buf, dst, nb) \
    _Pragma("unroll") \
    for (int n_ = 0; n_ < 2; ++n_) { \
        const int r_ = (wc & 1) * 64 + ((nb) + n_) * 16 + frow; \
        dst[n_][0] = *(const bf16x8*)&Bs[(buf)*16384 + (wc>>1)*8192 + r_*64 + ((fg     ^ (r_ & 7)) * 8)]; \
        dst[n_][1] = *(const bf16x8*)&Bs[(buf)*16384 + (wc>>1)*8192 + r_*64 + (((fg+4) ^ (r_ & 7)) * 8)]; \
    }

#define STAGE(gsrc, lreg, h, kt) do { \
        const bf16* g_ = (gsrc) + (size_t)((h) * 128) * K + (size_t)(kt) * 64; \
        bf16* l_ = (lreg) + (h) * 8192 + wave * 1024; \
        __builtin_amdgcn_global_load_lds((gvoid*)g_,           (lvoid*)l_,         16, 0, 0); \
        __builtin_amdgcn_global_load_lds((gvoid*)(g_ + rowK8), (lvoid*)(l_ + 512), 16, 0, 0); \
    } while (0)

#define QUAD(mh, nh, bb) \
    _Pragma("unroll") \
    for (int m_ = 0; m_ < 4; ++m_) \
        _Pragma("unroll") \
        for (int n_ = 0; n_ < 2; ++n_) { \
            acc[(mh)+m_][(nh)+n_] = __builtin_amdgcn_mfma_f32_16x16x32_bf16( \
                af[m_][0], bb[n_][0], acc[(mh)+m_][(nh)+n_], 0, 0, 0); \
            acc[(mh)+m_][(nh)+n_] = __builtin_amdgcn_mfma_f32_16x16x32_bf16( \
                af[m_][1], bb[n_][1], acc[(mh)+m_][(nh)+n_], 0, 0, 0); \
        }

template<int RELU, int TWO_BIAS, int OUTF32>
__global__ __launch_bounds__(512, 2)
void gemm256(const bf16* __restrict__ A, const bf16* __restrict__ Bm,
             const float* __restrict__ bias1, const float* __restrict__ bias2,
             void* __restrict__ Cp, int M, int N, int K)
{
    extern __shared__ bf16 smem[];          // 131072 B
    bf16* As = smem;                        // 4 regions x 8192 elems
    bf16* Bs = smem + 32768;

    const int tid  = threadIdx.x;
    const int wave = tid >> 6;
    const int lane = tid & 63;
    const int wr   = wave >> 2;             // M half (0..1): wave owns 128x64
    const int wc   = wave & 3;              // N quarter (0..3)
    const int bn = blockIdx.x;
    const int bm = blockIdx.y;

    // staging: lane -> row-in-chunk rc = lane>>3, swizzled granule (lane&7)^rc.
    // Wave stages chunks {wave*2, wave*2+1} (8 rows each) of every half-tile.
    const int rc  = lane >> 3;
    const int sgc = ((lane & 7) ^ rc) * 8;
    const bf16* aS0 = A  + (size_t)(bm * 256 + wave * 16 + rc) * K + sgc;
    const bf16* bS0 = Bm + (size_t)(bn * 256 + wave * 16 + rc) * K + sgc;
    const size_t rowK8 = (size_t)8 * K;

    // MFMA fragment addressing (16x16x32): lane holds [m=lane&15][k=(lane>>4)*8+..]
    const int frow = lane & 15;
    const int fg   = lane >> 4;

    bf16x8 af[4][2], bl[2][2], bh[2][2];
    f32x4 acc[8][4];
    #pragma unroll
    for (int i = 0; i < 8; ++i)
        #pragma unroll
        for (int j = 0; j < 4; ++j)
            acc[i][j] = {0.f, 0.f, 0.f, 0.f};

    const int NT = K >> 6;                  // K-tiles (even)
    const int NI = NT >> 1;                 // iterations (2 tiles each)

    // prologue: t0 -> P: B0,B1,A0,A1 ; t1 -> Q: B0,B1  (12 loads/wave)
    STAGE(bS0, Bs,         0, 0); STAGE(bS0, Bs,         1, 0);
    STAGE(aS0, As,         0, 0); STAGE(aS0, As,         1, 0);
    STAGE(bS0, Bs + 16384, 0, 1); STAGE(bS0, Bs + 16384, 1, 1);
    VMCNT(4);                               // t0 landed; Q.B (4) in flight
    BARS();

    for (int it = 0; it < NI; ++it) {
        const int t1 = 2 * it + 1;
        const int t2 = (2 * it + 2 < NT) ? 2 * it + 2 : 0;   // clamped tail
        const int t3 = t2 + 1;

        // ---- phase 1: P quadrant (m0-3, n0-1)
        RDA(0, 0);
        RDB(0, bl, 0);
        STAGE(aS0, As + 16384, 0, t1);
        BARS();
        __builtin_amdgcn_s_setprio(1); QUAD(0, 0, bl); __builtin_amdgcn_s_setprio(0);
        BARS();
        // ---- phase 2: (m0-3, n2-3)
        RDB(0, bh, 2);
        STAGE(aS0, As + 16384, 1, t1);
        BARS();
        __builtin_amdgcn_s_setprio(1); QUAD(0, 2, bh); __builtin_amdgcn_s_setprio(0);
        BARS();
        // ---- phase 3: (m4-7, n0-1)   [P.B fully read -> stage into it]
        RDA(0, 4);
        STAGE(bS0, Bs, 0, t2);
        BARS();
        __builtin_amdgcn_s_setprio(1); QUAD(4, 0, bl); __builtin_amdgcn_s_setprio(0);
        BARS();
        // ---- phase 4: (m4-7, n2-3)   [wait: Q data must be landed for ph5]
        STAGE(bS0, Bs, 1, t2);
        VMCNT(4);
        BARS();
        __builtin_amdgcn_s_setprio(1); QUAD(4, 2, bh); __builtin_amdgcn_s_setprio(0);
        BARS();
        // ---- phase 5: Q quadrant (m0-3, n0-1)  [P.A fully read -> stage]
        RDA(1, 0);
        RDB(1, bl, 0);
        STAGE(aS0, As, 0, t2);
        BARS();
        __builtin_amdgcn_s_setprio(1); QUAD(0, 0, bl); __builtin_amdgcn_s_setprio(0);
        BARS();
        // ---- phase 6: (m0-3, n2-3)
        RDB(1, bh, 2);
        STAGE(aS0, As, 1, t2);
        BARS();
        __builtin_amdgcn_s_setprio(1); QUAD(0, 2, bh); __builtin_amdgcn_s_setprio(0);
        BARS();
        // ---- phase 7: (m4-7, n0-1)   [Q.B fully read -> stage]
        RDA(1, 4);
        STAGE(bS0, Bs + 16384, 0, t3);
        BARS();
        __builtin_amdgcn_s_setprio(1); QUAD(4, 0, bl); __builtin_amdgcn_s_setprio(0);
        BARS();
        // ---- phase 8: (m4-7, n2-3)   [wait: P(t2) must be landed for ph1']
        STAGE(bS0, Bs + 16384, 1, t3);
        VMCNT(4);
        BARS();
        __builtin_amdgcn_s_setprio(1); QUAD(4, 2, bh); __builtin_amdgcn_s_setprio(0);
        BARS();
    }
    VMCNT(0);   // drain tail garbage stages before LDS dealloc

    // ---- epilogue: C/D layout col=lane&15, row=(lane>>4)*4+reg (m89/m91)
    const int crow0 = bm * 256 + wr * 128 + (lane >> 4) * 4;
    const int ccol0 = bn * 256 + wc * 64 + (lane & 15);

    #pragma unroll
    for (int n = 0; n < 4; ++n) {
        const int col = ccol0 + n * 16;
        float bv = bias1[col];
        if (TWO_BIAS) bv += bias2[col];
        #pragma unroll
        for (int m = 0; m < 8; ++m) {
            const int row = crow0 + m * 16;
            #pragma unroll
            for (int r = 0; r < 4; ++r) {
                float v = acc[m][n][r] + bv;
                if (RELU) v = fmaxf(v, 0.0f);
                if (OUTF32)
                    ((float*)Cp)[(size_t)(row + r) * N + col] = v;
                else
                    ((bf16*)Cp)[(size_t)(row + r) * N + col] = (bf16)v;
            }
        }
    }
}

static inline int cvt_blocks(size_t n) { return (int)((n / 8 + 255) / 256); }

extern "C" void kernel_launch(void* const* d_in, const int* in_sizes, int n_in,
                              void* d_out, int out_size, void* d_ws, size_t ws_size,
                              hipStream_t stream) {
    const float* x       = (const float*)d_in[0];  // [B,S,D_IN] fp32
    const float* W_init  = (const float*)d_in[1];  // [D_H, D_IN] fp32
    const float* b_init  = (const float*)d_in[2];  // [D_H] fp32
    const float* W_ih    = (const float*)d_in[3];  // [D_H, D_H] fp32
    const float* b_ih    = (const float*)d_in[4];  // [D_H] fp32
    const float* b_hh    = (const float*)d_in[5];  // [D_H] fp32
    const float* W_final = (const float*)d_in[6];  // [D_ACT, D_H] fp32
    const float* b_final = (const float*)d_in[7];  // [D_ACT] fp32
    float* out = (float*)d_out;                    // [B,S,D_ACT] fp32

    const int D_H   = in_sizes[2];               // 2048
    const int D_IN  = in_sizes[1] / D_H;         // 1024
    const int D_ACT = in_sizes[7];               // 1024
    const int M     = in_sizes[0] / D_IN;        // B*S = 32768

    const size_t nx  = (size_t)M * D_IN;
    const size_t nw1 = (size_t)D_H * D_IN;
    const size_t nw2 = (size_t)D_H * D_H;
    const size_t nw3 = (size_t)D_ACT * D_H;
    const size_t nh  = (size_t)M * D_H;

    // ws layout: [h: nh*2][a2: nh*2][w1b][w2b][w3b]; xb aliases a2's region
    // (x is dead before layer 2 writes a2 — same-stream ordering).
    char* ws  = (char*)d_ws;
    bf16* h   = (bf16*)ws;
    bf16* a2  = (bf16*)(ws + nh * 2);
    bf16* xb  = a2;                               // alias, see above
    bf16* w1b = (bf16*)(ws + nh * 4);
    bf16* w2b = w1b + nw1;
    bf16* w3b = w2b + nw2;

    // 128 KiB dynamic LDS opt-in (idempotent; harmless if already set)
    (void)hipFuncSetAttribute(reinterpret_cast<const void*>(&gemm256<1, 0, 0>),
                              hipFuncAttributeMaxDynamicSharedMemorySize, 131072);
    (void)hipFuncSetAttribute(reinterpret_cast<const void*>(&gemm256<1, 1, 0>),
                              hipFuncAttributeMaxDynamicSharedMemorySize, 131072);
    (void)hipFuncSetAttribute(reinterpret_cast<const void*>(&gemm256<0, 0, 1>),
                              hipFuncAttributeMaxDynamicSharedMemorySize, 131072);

    cvt_f32_bf16<<<cvt_blocks(nx),  256, 0, stream>>>(x,       xb,  (int)(nx  / 8));
    cvt_f32_bf16<<<cvt_blocks(nw1), 256, 0, stream>>>(W_init,  w1b, (int)(nw1 / 8));
    cvt_f32_bf16<<<cvt_blocks(nw2), 256, 0, stream>>>(W_ih,    w2b, (int)(nw2 / 8));
    cvt_f32_bf16<<<cvt_blocks(nw3), 256, 0, stream>>>(W_final, w3b, (int)(nw3 / 8));

    // layer 1: h = relu(x @ W_init^T + b_init)          [bf16 out]
    gemm256<1, 0, 0><<<dim3(D_H / 256, M / 256), 512, 131072, stream>>>(
        xb, w1b, b_init, nullptr, h, M, D_H, D_IN);

    // layer 2: a2 = relu(h @ W_ih^T + b_ih + b_hh)      [bf16 out]
    gemm256<1, 1, 0><<<dim3(D_H / 256, M / 256), 512, 131072, stream>>>(
        h, w2b, b_ih, b_hh, a2, M, D_H, D_H);

    // layer 3: out = a2 @ W_final^T + b_final           [fp32 out]
    gemm256<0, 0, 1><<<dim3(D_ACT / 256, M / 256), 512, 131072, stream>>>(
        a2, w3b, b_final, nullptr, out, M, D_ACT, D_H);
}

// Round 2
// 702.567 us; speedup vs baseline: 1.1278x; 1.1072x over previous
//
#include <hip/hip_runtime.h>
#include <hip/hip_bf16.h>
#include <stdint.h>
#include <stddef.h>

typedef __bf16 bf16;
typedef __bf16 bf16x8 __attribute__((ext_vector_type(8)));
typedef float f32x4 __attribute__((ext_vector_type(4)));
typedef __attribute__((address_space(1))) void gvoid;
typedef __attribute__((address_space(3))) void lvoid;

#define FENCE() asm volatile("" ::: "memory")
#define VMCNT(n) asm volatile("s_waitcnt vmcnt(" #n ")" ::: "memory")
#define BARS() do { FENCE(); __builtin_amdgcn_s_barrier(); FENCE(); } while (0)

// ---------------- fp32 -> bf16 elementwise convert, 8 elem/thread ----------------
__global__ __launch_bounds__(256)
void cvt_f32_bf16(const float* __restrict__ in, bf16* __restrict__ out, int n8)
{
    int i = blockIdx.x * 256 + threadIdx.x;
    if (i >= n8) return;
    const f32x4* p = (const f32x4*)in + (size_t)i * 2;
    f32x4 a = p[0], b = p[1];
    bf16x8 o;
    o[0] = (bf16)a[0]; o[1] = (bf16)a[1]; o[2] = (bf16)a[2]; o[3] = (bf16)a[3];
    o[4] = (bf16)b[0]; o[5] = (bf16)b[1]; o[6] = (bf16)b[2]; o[7] = (bf16)b[3];
    *((bf16x8*)out + i) = o;
}

// ---------------- 256x256 / BK=64 / 8-wave / 8-phase GEMM, 1 barrier/phase ------
// C[M,N] = act(A[M,K] * B[N,K]^T + bias1 (+bias2)). bf16 in, fp32 MFMA accum.
// Requires M%256==0, N%256==0, K%128==0.
//
// LDS (128 KiB dynamic): A = 2 bufs x 2 halves x [128 rows][64 cols] bf16,
// B same. Swizzle: LDS row r, 16B-granule slot s holds global granule
// s ^ (r&7); XOR applied on the global_load_lds SOURCE (dest must stay
// linear), ds_reads XOR back. Measured 0 bank conflicts.
//
// Schedule per iteration (2 K-tiles: P=buf0 even, Q=buf1 odd), ONE barrier
// per phase:  { ds_reads | stage | [vmcnt] | s_barrier | 16 MFMA }.
// WAR safety rule for a single barrier: a stage at phase p may only target a
// region whose last ds_read was at phase <= p-2  (a wave passing bar(p-1)
// has lgkm-completed its reads of p-2 before its mfma(p-2), which precedes
// bar(p-1) in program order). Staging assignment (all satisfy >=2):
//   ph1: Q.A0(t1)   [Q.A last read ph6-prev, d=3]
//   ph2: Q.A1(t1)   [d=4]
//   ph3: --
//   ph4: P.B0+P.B1(t2) [P.B last read ph2, d=2]  + VMCNT(4)
//   ph5: P.A0(t2)   [P.A last read ph3, d=2]
//   ph6: P.A1(t2)   [d=3]
//   ph7: --
//   ph8: Q.B0+Q.B1(t3) [Q.B last read ph6, d=2]  + VMCNT(4)
// vmcnt(4): at ph4, outstanding = QB(t1)4 + QA(t1)4 + PB(t2)4 = 12; waiting
// to 4 drains all of Q(t1) before ph5 reads it. Symmetric at ph8 for P(t2).
// Tail iterations clamp t2/t3 to tile 0 (in-bounds garbage into dead
// regions) so counts stay uniform; VMCNT(0) after the loop.
#define RDA(buf, mh) \
    _Pragma("unroll") \
    for (int h_ = 0; h_ < 2; ++h_) \
        _Pragma("unroll") \
        for (int m_ = 0; m_ < 4; ++m_) { \
            const int r_ = ((mh) + m_) * 16 + frow; \
            af[m_][h_] = *(const bf16x8*)&As[(buf)*16384 + wr*8192 + r_*64 \
                                            + (((fg + 4*h_) ^ (r_ & 7)) * 8)]; \
        }

#define RDB(buf, dst, nb) \
    _Pragma("unroll") \
    for (int h_ = 0; h_ < 2; ++h_) \
        _Pragma("unroll") \
        for (int n_ = 0; n_ < 2; ++n_) { \
            const int r_ = (wc & 1) * 64 + ((nb) + n_) * 16 + frow; \
            dst[n_][h_] = *(const bf16x8*)&Bs[(buf)*16384 + (wc>>1)*8192 + r_*64 \
                                             + (((fg + 4*h_) ^ (r_ & 7)) * 8)]; \
        }

#define STAGE(gsrc, lreg, h, kt) do { \
        const bf16* g_ = (gsrc) + (size_t)((h) * 128) * K + (size_t)(kt) * 64; \
        bf16* l_ = (lreg) + (h) * 8192 + wave * 1024; \
        __builtin_amdgcn_global_load_lds((gvoid*)g_,           (lvoid*)l_,         16, 0, 0); \
        __builtin_amdgcn_global_load_lds((gvoid*)(g_ + rowK8), (lvoid*)(l_ + 512), 16, 0, 0); \
    } while (0)

// k-half outer: no back-to-back dependent MFMAs; first mfma depends on the
// earliest-issued ds_reads (incremental lgkm overlap).
#define QUAD(mh, nh, bb) \
    _Pragma("unroll") \
    for (int h_ = 0; h_ < 2; ++h_) \
        _Pragma("unroll") \
        for (int m_ = 0; m_ < 4; ++m_) \
            _Pragma("unroll") \
            for (int n_ = 0; n_ < 2; ++n_) \
                acc[(mh)+m_][(nh)+n_] = __builtin_amdgcn_mfma_f32_16x16x32_bf16( \
                    af[m_][h_], bb[n_][h_], acc[(mh)+m_][(nh)+n_], 0, 0, 0);

#define MFMA_PH(mh, nh, bb) do { \
        __builtin_amdgcn_s_setprio(1); QUAD(mh, nh, bb); __builtin_amdgcn_s_setprio(0); \
    } while (0)

template<int RELU, int TWO_BIAS, int OUTF32>
__global__ __launch_bounds__(512, 2)
void gemm256(const bf16* __restrict__ A, const bf16* __restrict__ Bm,
             const float* __restrict__ bias1, const float* __restrict__ bias2,
             void* __restrict__ Cp, int M, int N, int K)
{
    extern __shared__ bf16 smem[];          // 131072 B
    bf16* As = smem;                        // 4 regions x 8192 elems
    bf16* Bs = smem + 32768;

    const int tid  = threadIdx.x;
    const int wave = tid >> 6;
    const int lane = tid & 63;
    const int wr   = wave >> 2;             // M half (0..1): wave owns 128x64
    const int wc   = wave & 3;              // N quarter (0..3)

    // XCD-aware bijective swizzle: nwg % 8 == 0 for all our grids (1024/512).
    // Default HW round-robins wgid%8 across XCDs -> each XCD gets a
    // contiguous chunk of the bm-major tile space (A-panel L2 reuse).
    const int nwg = gridDim.x * gridDim.y;
    int wg = blockIdx.y * gridDim.x + blockIdx.x;
    wg = (wg & 7) * (nwg >> 3) + (wg >> 3);
    const int bn = wg % gridDim.x;
    const int bm = wg / gridDim.x;

    // staging: lane -> row-in-chunk rc = lane>>3, swizzled granule (lane&7)^rc.
    const int rc  = lane >> 3;
    const int sgc = ((lane & 7) ^ rc) * 8;
    const bf16* aS0 = A  + (size_t)(bm * 256 + wave * 16 + rc) * K + sgc;
    const bf16* bS0 = Bm + (size_t)(bn * 256 + wave * 16 + rc) * K + sgc;
    const size_t rowK8 = (size_t)8 * K;

    // MFMA fragment addressing (16x16x32): lane holds [m=lane&15][k=(lane>>4)*8+..]
    const int frow = lane & 15;
    const int fg   = lane >> 4;

    bf16x8 af[4][2], bl[2][2], bh[2][2];
    f32x4 acc[8][4];
    #pragma unroll
    for (int i = 0; i < 8; ++i)
        #pragma unroll
        for (int j = 0; j < 4; ++j)
            acc[i][j] = {0.f, 0.f, 0.f, 0.f};

    const int NT = K >> 6;                  // K-tiles (even)
    const int NI = NT >> 1;                 // iterations (2 tiles each)

    // prologue: t0 -> P: B0,B1,A0,A1 ; t1 -> Q: B0,B1  (12 loads/wave)
    STAGE(bS0, Bs,         0, 0); STAGE(bS0, Bs,         1, 0);
    STAGE(aS0, As,         0, 0); STAGE(aS0, As,         1, 0);
    STAGE(bS0, Bs + 16384, 0, 1); STAGE(bS0, Bs + 16384, 1, 1);
    VMCNT(4);                               // t0 landed; Q.B(t1) 4 in flight
    BARS();

    for (int it = 0; it < NI; ++it) {
        const int t1 = 2 * it + 1;
        const int t2 = (2 * it + 2 < NT) ? 2 * it + 2 : 0;   // clamped tail
        const int t3 = t2 + 1;

        // ---- phase 1: P (m0-3, n0-1)
        RDB(0, bl, 0);
        RDA(0, 0);
        STAGE(aS0, As + 16384, 0, t1);
        BARS();
        MFMA_PH(0, 0, bl);
        // ---- phase 2: P (m0-3, n2-3)
        RDB(0, bh, 2);
        STAGE(aS0, As + 16384, 1, t1);
        BARS();
        MFMA_PH(0, 2, bh);
        // ---- phase 3: P (m4-7, n0-1)
        RDA(0, 4);
        BARS();
        MFMA_PH(4, 0, bl);
        // ---- phase 4: P (m4-7, n2-3)  [stage P.B(t2); drain Q(t1) for ph5]
        STAGE(bS0, Bs, 0, t2);
        STAGE(bS0, Bs, 1, t2);
        VMCNT(4);
        BARS();
        MFMA_PH(4, 2, bh);
        // ---- phase 5: Q (m0-3, n0-1)
        RDB(1, bl, 0);
        RDA(1, 0);
        STAGE(aS0, As, 0, t2);
        BARS();
        MFMA_PH(0, 0, bl);
        // ---- phase 6: Q (m0-3, n2-3)
        RDB(1, bh, 2);
        STAGE(aS0, As, 1, t2);
        BARS();
        MFMA_PH(0, 2, bh);
        // ---- phase 7: Q (m4-7, n0-1)
        RDA(1, 4);
        BARS();
        MFMA_PH(4, 0, bl);
        // ---- phase 8: Q (m4-7, n2-3)  [stage Q.B(t3); drain P(t2) for ph1']
        STAGE(bS0, Bs + 16384, 0, t3);
        STAGE(bS0, Bs + 16384, 1, t3);
        VMCNT(4);
        BARS();
        MFMA_PH(4, 2, bh);
    }
    VMCNT(0);   // drain tail garbage stages before LDS dealloc

    // ---- epilogue: C/D layout col=lane&15, row=(lane>>4)*4+reg (m89/m91)
    // m,r outer / n inner: per (m,r) the wave's 4 n-stores cover 64 consecutive
    // cols per row in consecutive instructions -> full-line write combining.
    const int crow0 = bm * 256 + wr * 128 + (lane >> 4) * 4;
    const int ccol0 = bn * 256 + wc * 64 + (lane & 15);

    float bv[4];
    #pragma unroll
    for (int n = 0; n < 4; ++n) {
        bv[n] = bias1[ccol0 + n * 16];
        if (TWO_BIAS) bv[n] += bias2[ccol0 + n * 16];
    }

    #pragma unroll
    for (int m = 0; m < 8; ++m) {
        #pragma unroll
        for (int r = 0; r < 4; ++r) {
            const size_t row = (size_t)(crow0 + m * 16 + r);
            #pragma unroll
            for (int n = 0; n < 4; ++n) {
                float v = acc[m][n][r] + bv[n];
                if (RELU) v = fmaxf(v, 0.0f);
                if (OUTF32)
                    ((float*)Cp)[row * N + ccol0 + n * 16] = v;
                else
                    ((bf16*)Cp)[row * N + ccol0 + n * 16] = (bf16)v;
            }
        }
    }
}

static inline int cvt_blocks(size_t n) { return (int)((n / 8 + 255) / 256); }

extern "C" void kernel_launch(void* const* d_in, const int* in_sizes, int n_in,
                              void* d_out, int out_size, void* d_ws, size_t ws_size,
                              hipStream_t stream) {
    const float* x       = (const float*)d_in[0];  // [B,S,D_IN] fp32
    const float* W_init  = (const float*)d_in[1];  // [D_H, D_IN] fp32
    const float* b_init  = (const float*)d_in[2];  // [D_H] fp32
    const float* W_ih    = (const float*)d_in[3];  // [D_H, D_H] fp32
    const float* b_ih    = (const float*)d_in[4];  // [D_H] fp32
    const float* b_hh    = (const float*)d_in[5];  // [D_H] fp32
    const float* W_final = (const float*)d_in[6];  // [D_ACT, D_H] fp32
    const float* b_final = (const float*)d_in[7];  // [D_ACT] fp32
    float* out = (float*)d_out;                    // [B,S,D_ACT] fp32

    const int D_H   = in_sizes[2];               // 2048
    const int D_IN  = in_sizes[1] / D_H;         // 1024
    const int D_ACT = in_sizes[7];               // 1024
    const int M     = in_sizes[0] / D_IN;        // B*S = 32768

    const size_t nx  = (size_t)M * D_IN;
    const size_t nw1 = (size_t)D_H * D_IN;
    const size_t nw2 = (size_t)D_H * D_H;
    const size_t nw3 = (size_t)D_ACT * D_H;
    const size_t nh  = (size_t)M * D_H;

    // ws layout: [h: nh*2][a2: nh*2][w1b][w2b][w3b]; xb aliases a2's region
    // (x is dead before layer 2 writes a2 — same-stream ordering).
    char* ws  = (char*)d_ws;
    bf16* h   = (bf16*)ws;
    bf16* a2  = (bf16*)(ws + nh * 2);
    bf16* xb  = a2;                               // alias, see above
    bf16* w1b = (bf16*)(ws + nh * 4);
    bf16* w2b = w1b + nw1;
    bf16* w3b = w2b + nw2;

    // 128 KiB dynamic LDS opt-in (idempotent; harmless if already set)
    (void)hipFuncSetAttribute(reinterpret_cast<const void*>(&gemm256<1, 0, 0>),
                              hipFuncAttributeMaxDynamicSharedMemorySize, 131072);
    (void)hipFuncSetAttribute(reinterpret_cast<const void*>(&gemm256<1, 1, 0>),
                              hipFuncAttributeMaxDynamicSharedMemorySize, 131072);
    (void)hipFuncSetAttribute(reinterpret_cast<const void*>(&gemm256<0, 0, 1>),
                              hipFuncAttributeMaxDynamicSharedMemorySize, 131072);

    cvt_f32_bf16<<<cvt_blocks(nx),  256, 0, stream>>>(x,       xb,  (int)(nx  / 8));
    cvt_f32_bf16<<<cvt_blocks(nw1), 256, 0, stream>>>(W_init,  w1b, (int)(nw1 / 8));
    cvt_f32_bf16<<<cvt_blocks(nw2), 256, 0, stream>>>(W_ih,    w2b, (int)(nw2 / 8));
    cvt_f32_bf16<<<cvt_blocks(nw3), 256, 0, stream>>>(W_final, w3b, (int)(nw3 / 8));

    // layer 1: h = relu(x @ W_init^T + b_init)          [bf16 out]
    gemm256<1, 0, 0><<<dim3(D_H / 256, M / 256), 512, 131072, stream>>>(
        xb, w1b, b_init, nullptr, h, M, D_H, D_IN);

    // layer 2: a2 = relu(h @ W_ih^T + b_ih + b_hh)      [bf16 out]
    gemm256<1, 1, 0><<<dim3(D_H / 256, M / 256), 512, 131072, stream>>>(
        h, w2b, b_ih, b_hh, a2, M, D_H, D_H);

    // layer 3: out = a2 @ W_final^T + b_final           [fp32 out]
    gemm256<0, 0, 1><<<dim3(D_ACT / 256, M / 256), 512, 131072, stream>>>(
        a2, w3b, b_final, nullptr, out, M, D_ACT, D_H);
}

// Round 3
// 699.756 us; speedup vs baseline: 1.1323x; 1.0040x over previous
//
#include <hip/hip_runtime.h>
#include <hip/hip_bf16.h>
#include <stdint.h>
#include <stddef.h>

typedef __bf16 bf16;
typedef __bf16 bf16x8 __attribute__((ext_vector_type(8)));
typedef float f32x4 __attribute__((ext_vector_type(4)));
typedef __attribute__((address_space(1))) void gvoid;
typedef __attribute__((address_space(3))) void lvoid;

#define FENCE() asm volatile("" ::: "memory")
#define VMCNT(n) asm volatile("s_waitcnt vmcnt(" #n ")" ::: "memory")
#define BARS() do { FENCE(); __builtin_amdgcn_s_barrier(); FENCE(); } while (0)

// ---------------- fp32 -> bf16 elementwise convert, 8 elem/thread ----------------
__global__ __launch_bounds__(256)
void cvt_f32_bf16(const float* __restrict__ in, bf16* __restrict__ out, int n8)
{
    int i = blockIdx.x * 256 + threadIdx.x;
    if (i >= n8) return;
    const f32x4* p = (const f32x4*)in + (size_t)i * 2;
    f32x4 a = p[0], b = p[1];
    bf16x8 o;
    o[0] = (bf16)a[0]; o[1] = (bf16)a[1]; o[2] = (bf16)a[2]; o[3] = (bf16)a[3];
    o[4] = (bf16)b[0]; o[5] = (bf16)b[1]; o[6] = (bf16)b[2]; o[7] = (bf16)b[3];
    *((bf16x8*)out + i) = o;
}

// ---------------- 256x256 / BK=64 / 8-wave / 8-phase GEMM, 1 barrier/phase ------
// C[M,N] = act(A[M,K] * B[N,K]^T + bias1 (+bias2)). bf16 in, fp32 MFMA accum.
// Requires M%256==0, N%256==0, K%128==0.
//
// LDS (128 KiB dynamic): A = 2 bufs x 2 halves x [128 rows][64 cols] bf16,
// B same. Swizzle: LDS row r, 16B-granule slot s holds global granule
// s ^ (r&7); XOR applied on the global_load_lds SOURCE (dest must stay
// linear), ds_reads XOR back. Measured 0 bank conflicts.
//
// ds_read addressing diet (R3): every fragment row offset is a multiple of
// 8, so the swizzle term (fg+4h)^(r&7) == (fg+4h)^(frow&7) is FRAGMENT-
// INDEPENDENT. All 48 reads/iter = one of 4 per-lane base pointers + a
// compile-time constant (max byte offset 47104 < 64Ki) -> bare
// ds_read_b128 offset:imm, zero per-read VALU. (R2's per-read addr calc
// was ~2000 VALU-cyc/SIMD/iter on the post-barrier critical path.)
//
// Schedule per iteration (2 K-tiles: P=buf0 even, Q=buf1 odd), ONE barrier
// per phase:  { ds_reads | stage | [vmcnt] | s_barrier | 16 MFMA }.
// WAR rule: a stage at phase p only targets a region last-read at <= p-2.
// vmcnt(4) at ph4 drains Q(t1) before ph5 reads it; at ph8 drains P(t2).
// Tail iterations clamp t2/t3 to tile 0 (in-bounds garbage into dead
// regions) so counts stay uniform; VMCNT(0) after the loop.
#define RDA(buf, mh) \
    _Pragma("unroll") \
    for (int m_ = 0; m_ < 4; ++m_) { \
        af[m_][0] = *(const bf16x8*)(rdA0 + (buf) * 16384 + ((mh) + m_) * 1024); \
        af[m_][1] = *(const bf16x8*)(rdA1 + (buf) * 16384 + ((mh) + m_) * 1024); \
    }

#define RDB(buf, dst, nb) \
    _Pragma("unroll") \
    for (int n_ = 0; n_ < 2; ++n_) { \
        dst[n_][0] = *(const bf16x8*)(rdB0 + (buf) * 16384 + ((nb) + n_) * 1024); \
        dst[n_][1] = *(const bf16x8*)(rdB1 + (buf) * 16384 + ((nb) + n_) * 1024); \
    }

#define STAGE(gsrc, lreg, h, kt) do { \
        const bf16* g_ = (gsrc) + (size_t)((h) * 128) * K + (size_t)(kt) * 64; \
        bf16* l_ = (lreg) + (h) * 8192 + wave * 1024; \
        __builtin_amdgcn_global_load_lds((gvoid*)g_,           (lvoid*)l_,         16, 0, 0); \
        __builtin_amdgcn_global_load_lds((gvoid*)(g_ + rowK8), (lvoid*)(l_ + 512), 16, 0, 0); \
    } while (0)

// k-half outer: no back-to-back dependent MFMAs; first mfma depends on the
// earliest-issued ds_reads (incremental lgkm overlap).
#define QUAD(mh, nh, bb) \
    _Pragma("unroll") \
    for (int h_ = 0; h_ < 2; ++h_) \
        _Pragma("unroll") \
        for (int m_ = 0; m_ < 4; ++m_) \
            _Pragma("unroll") \
            for (int n_ = 0; n_ < 2; ++n_) \
                acc[(mh)+m_][(nh)+n_] = __builtin_amdgcn_mfma_f32_16x16x32_bf16( \
                    af[m_][h_], bb[n_][h_], acc[(mh)+m_][(nh)+n_], 0, 0, 0);

#define MFMA_PH(mh, nh, bb) do { \
        __builtin_amdgcn_s_setprio(1); QUAD(mh, nh, bb); __builtin_amdgcn_s_setprio(0); \
    } while (0)

template<int RELU, int TWO_BIAS, int OUTF32>
__global__ __launch_bounds__(512, 2)
void gemm256(const bf16* __restrict__ A, const bf16* __restrict__ Bm,
             const float* __restrict__ bias1, const float* __restrict__ bias2,
             void* __restrict__ Cp, int M, int N, int K)
{
    extern __shared__ bf16 smem[];          // 131072 B
    bf16* As = smem;                        // 4 regions x 8192 elems
    bf16* Bs = smem + 32768;

    const int tid  = threadIdx.x;
    const int wave = tid >> 6;
    const int lane = tid & 63;
    const int wr   = wave >> 2;             // M half (0..1): wave owns 128x64
    const int wc   = wave & 3;              // N quarter (0..3)

    // XCD-aware bijective swizzle: nwg % 8 == 0 for all our grids (1024/512).
    const int nwg = gridDim.x * gridDim.y;
    int wg = blockIdx.y * gridDim.x + blockIdx.x;
    wg = (wg & 7) * (nwg >> 3) + (wg >> 3);
    const int bn = wg % gridDim.x;
    const int bm = wg / gridDim.x;

    // staging: lane -> row-in-chunk rc = lane>>3, swizzled granule (lane&7)^rc.
    const int rc  = lane >> 3;
    const int sgc = ((lane & 7) ^ rc) * 8;
    const bf16* aS0 = A  + (size_t)(bm * 256 + wave * 16 + rc) * K + sgc;
    const bf16* bS0 = Bm + (size_t)(bn * 256 + wave * 16 + rc) * K + sgc;
    const size_t rowK8 = (size_t)8 * K;

    // MFMA fragment addressing (16x16x32): lane holds [m=lane&15][k=(lane>>4)*8+..]
    const int frow = lane & 15;
    const int fg   = lane >> 4;
    const int fsw  = frow & 7;

    // Precomputed LDS read bases (swizzle folded in; see header comment).
    const bf16* rdA0 = As + wr * 8192 + frow * 64 + ((fg ^ fsw) << 3);
    const bf16* rdA1 = As + wr * 8192 + frow * 64 + (((fg + 4) ^ fsw) << 3);
    const bf16* rdB0 = Bs + (wc >> 1) * 8192 + (wc & 1) * 4096 + frow * 64 + ((fg ^ fsw) << 3);
    const bf16* rdB1 = Bs + (wc >> 1) * 8192 + (wc & 1) * 4096 + frow * 64 + (((fg + 4) ^ fsw) << 3);

    bf16x8 af[4][2], bl[2][2], bh[2][2];
    f32x4 acc[8][4];
    #pragma unroll
    for (int i = 0; i < 8; ++i)
        #pragma unroll
        for (int j = 0; j < 4; ++j)
            acc[i][j] = {0.f, 0.f, 0.f, 0.f};

    const int NT = K >> 6;                  // K-tiles (even)
    const int NI = NT >> 1;                 // iterations (2 tiles each)

    // prologue: t0 -> P: B0,B1,A0,A1 ; t1 -> Q: B0,B1  (12 loads/wave)
    STAGE(bS0, Bs,         0, 0); STAGE(bS0, Bs,         1, 0);
    STAGE(aS0, As,         0, 0); STAGE(aS0, As,         1, 0);
    STAGE(bS0, Bs + 16384, 0, 1); STAGE(bS0, Bs + 16384, 1, 1);
    VMCNT(4);                               // t0 landed; Q.B(t1) 4 in flight
    BARS();

    for (int it = 0; it < NI; ++it) {
        const int t1 = 2 * it + 1;
        const int t2 = (2 * it + 2 < NT) ? 2 * it + 2 : 0;   // clamped tail
        const int t3 = t2 + 1;

        // ---- phase 1: P (m0-3, n0-1)
        RDB(0, bl, 0);
        RDA(0, 0);
        STAGE(aS0, As + 16384, 0, t1);
        BARS();
        MFMA_PH(0, 0, bl);
        // ---- phase 2: P (m0-3, n2-3)
        RDB(0, bh, 2);
        STAGE(aS0, As + 16384, 1, t1);
        BARS();
        MFMA_PH(0, 2, bh);
        // ---- phase 3: P (m4-7, n0-1)
        RDA(0, 4);
        BARS();
        MFMA_PH(4, 0, bl);
        // ---- phase 4: P (m4-7, n2-3)  [stage P.B(t2); drain Q(t1) for ph5]
        STAGE(bS0, Bs, 0, t2);
        STAGE(bS0, Bs, 1, t2);
        VMCNT(4);
        BARS();
        MFMA_PH(4, 2, bh);
        // ---- phase 5: Q (m0-3, n0-1)
        RDB(1, bl, 0);
        RDA(1, 0);
        STAGE(aS0, As, 0, t2);
        BARS();
        MFMA_PH(0, 0, bl);
        // ---- phase 6: Q (m0-3, n2-3)
        RDB(1, bh, 2);
        STAGE(aS0, As, 1, t2);
        BARS();
        MFMA_PH(0, 2, bh);
        // ---- phase 7: Q (m4-7, n0-1)
        RDA(1, 4);
        BARS();
        MFMA_PH(4, 0, bl);
        // ---- phase 8: Q (m4-7, n2-3)  [stage Q.B(t3); drain P(t2) for ph1']
        STAGE(bS0, Bs + 16384, 0, t3);
        STAGE(bS0, Bs + 16384, 1, t3);
        VMCNT(4);
        BARS();
        MFMA_PH(4, 2, bh);
    }
    VMCNT(0);   // drain tail garbage stages before LDS dealloc

    // ---- epilogue: C/D layout col=lane&15, row=(lane>>4)*4+reg (m89/m91)
    const int crow0 = bm * 256 + wr * 128 + (lane >> 4) * 4;
    const int ccol0 = bn * 256 + wc * 64 + (lane & 15);

    float bv[4];
    #pragma unroll
    for (int n = 0; n < 4; ++n) {
        bv[n] = bias1[ccol0 + n * 16];
        if (TWO_BIAS) bv[n] += bias2[ccol0 + n * 16];
    }

    #pragma unroll
    for (int m = 0; m < 8; ++m) {
        #pragma unroll
        for (int r = 0; r < 4; ++r) {
            const size_t row = (size_t)(crow0 + m * 16 + r);
            #pragma unroll
            for (int n = 0; n < 4; ++n) {
                float v = acc[m][n][r] + bv[n];
                if (RELU) v = fmaxf(v, 0.0f);
                if (OUTF32)
                    ((float*)Cp)[row * N + ccol0 + n * 16] = v;
                else
                    ((bf16*)Cp)[row * N + ccol0 + n * 16] = (bf16)v;
            }
        }
    }
}

static inline int cvt_blocks(size_t n) { return (int)((n / 8 + 255) / 256); }

extern "C" void kernel_launch(void* const* d_in, const int* in_sizes, int n_in,
                              void* d_out, int out_size, void* d_ws, size_t ws_size,
                              hipStream_t stream) {
    const float* x       = (const float*)d_in[0];  // [B,S,D_IN] fp32
    const float* W_init  = (const float*)d_in[1];  // [D_H, D_IN] fp32
    const float* b_init  = (const float*)d_in[2];  // [D_H] fp32
    const float* W_ih    = (const float*)d_in[3];  // [D_H, D_H] fp32
    const float* b_ih    = (const float*)d_in[4];  // [D_H] fp32
    const float* b_hh    = (const float*)d_in[5];  // [D_H] fp32
    const float* W_final = (const float*)d_in[6];  // [D_ACT, D_H] fp32
    const float* b_final = (const float*)d_in[7];  // [D_ACT] fp32
    float* out = (float*)d_out;                    // [B,S,D_ACT] fp32

    const int D_H   = in_sizes[2];               // 2048
    const int D_IN  = in_sizes[1] / D_H;         // 1024
    const int D_ACT = in_sizes[7];               // 1024
    const int M     = in_sizes[0] / D_IN;        // B*S = 32768

    const size_t nx  = (size_t)M * D_IN;
    const size_t nw1 = (size_t)D_H * D_IN;
    const size_t nw2 = (size_t)D_H * D_H;
    const size_t nw3 = (size_t)D_ACT * D_H;
    const size_t nh  = (size_t)M * D_H;

    // ws layout: [h: nh*2][a2: nh*2][w1b][w2b][w3b]; xb aliases a2's region
    // (x is dead before layer 2 writes a2 — same-stream ordering).
    char* ws  = (char*)d_ws;
    bf16* h   = (bf16*)ws;
    bf16* a2  = (bf16*)(ws + nh * 2);
    bf16* xb  = a2;                               // alias, see above
    bf16* w1b = (bf16*)(ws + nh * 4);
    bf16* w2b = w1b + nw1;
    bf16* w3b = w2b + nw2;

    // 128 KiB dynamic LDS opt-in (idempotent; harmless if already set)
    (void)hipFuncSetAttribute(reinterpret_cast<const void*>(&gemm256<1, 0, 0>),
                              hipFuncAttributeMaxDynamicSharedMemorySize, 131072);
    (void)hipFuncSetAttribute(reinterpret_cast<const void*>(&gemm256<1, 1, 0>),
                              hipFuncAttributeMaxDynamicSharedMemorySize, 131072);
    (void)hipFuncSetAttribute(reinterpret_cast<const void*>(&gemm256<0, 0, 1>),
                              hipFuncAttributeMaxDynamicSharedMemorySize, 131072);

    cvt_f32_bf16<<<cvt_blocks(nx),  256, 0, stream>>>(x,       xb,  (int)(nx  / 8));
    cvt_f32_bf16<<<cvt_blocks(nw1), 256, 0, stream>>>(W_init,  w1b, (int)(nw1 / 8));
    cvt_f32_bf16<<<cvt_blocks(nw2), 256, 0, stream>>>(W_ih,    w2b, (int)(nw2 / 8));
    cvt_f32_bf16<<<cvt_blocks(nw3), 256, 0, stream>>>(W_final, w3b, (int)(nw3 / 8));

    // layer 1: h = relu(x @ W_init^T + b_init)          [bf16 out]
    gemm256<1, 0, 0><<<dim3(D_H / 256, M / 256), 512, 131072, stream>>>(
        xb, w1b, b_init, nullptr, h, M, D_H, D_IN);

    // layer 2: a2 = relu(h @ W_ih^T + b_ih + b_hh)      [bf16 out]
    gemm256<1, 1, 0><<<dim3(D_H / 256, M / 256), 512, 131072, stream>>>(
        h, w2b, b_ih, b_hh, a2, M, D_H, D_H);

    // layer 3: out = a2 @ W_final^T + b_final           [fp32 out]
    gemm256<0, 0, 1><<<dim3(D_ACT / 256, M / 256), 512, 131072, stream>>>(
        a2, w3b, b_final, nullptr, out, M, D_ACT, D_H);
}